// Round 1
// 557.077 us; speedup vs baseline: 1.0275x; 1.0275x over previous
//
#include <hip/hip_runtime.h>

// KPConv fused kernel for MI355X (gfx950) — round 1 polish.
// Shapes: N=50000 points, 32 neighbors, K=15 kernel pts, Cin=Cout=64, fp32 in/out.
// Changes vs prev: (1) weights pre-converted to frag-ordered bf16 in d_ws (prep kernel),
// (2) x staged via coalesced float4 loads -> bf16 LDS subtiles -> ds_read_b64_tr_b16
//     hardware-transpose fragment reads (replaces 128 stride-256B scalar loads/wave),
// (3) stage-1 MFMA operands swapped (A=x^T, B=w) so the A2 spill is 4x ds_write_b64,
// (4) intra-stage-1 __syncthreads removed (wa/xs are wave-local; DS pipe is in-order),
// (5) native __bf16 casts (compiler emits packed v_cvt_pk_bf16_f32).

typedef __attribute__((ext_vector_type(8))) short bf16x8;
typedef __attribute__((ext_vector_type(4))) short short4v;
typedef __attribute__((ext_vector_type(4))) float f32x4;

#define NPTS        50000
#define PTS_PER_WG  16
#define KP_INV      (1.0f / 0.06f)
#define WP_ELEMS    (120 * 64 * 8)   // 61440 bf16 = 122880 B in d_ws

static __device__ __forceinline__ short fbf(float f) {
    union { __bf16 h; short s; } u; u.h = (__bf16)f; return u.s;
}

// weights [15][64][64] f32 -> wp[ch][d][j] bf16, ch = k2>>3 (k2 = k*64+cin), j = k2&7.
// Stage-2 B-frag then loads 16 B contiguous per lane.
__global__ void prep_weights(const float* __restrict__ w, unsigned short* __restrict__ wp) {
    const int ch = blockIdx.x;          // 0..119
    const int t  = threadIdx.x;         // 0..511
    const int d  = t >> 3, j = t & 7;
    wp[(ch * 64 + d) * 8 + j] = (unsigned short)fbf(w[(ch * 8 + j) * 64 + d]);
}

__launch_bounds__(256, 3)
__global__ void kpconv_kernel(const float* __restrict__ q_pts,
                              const float* __restrict__ neighbors,
                              const float* __restrict__ x,
                              const float* __restrict__ kp,
                              const float* __restrict__ weights,
                              const unsigned short* __restrict__ wp,
                              float* __restrict__ out) {
    // per-wave w buffer: rows k=0..15, cols m=0..31, row stride 40 (16B-aligned b128 reads)
    __shared__ __align__(16) unsigned short wa[4][640];
    // per-wave x staging: 32 subtiles of [4 m][16 c] bf16 (128 B each), slot = (m>>2)*4 + (c>>4)
    __shared__ __align__(16) unsigned short xs[4][2048];
    // weighted (stage-2 A operand): [16 pts][120 chunks][8], chunk index sigma-swizzled
    __shared__ __align__(16) unsigned short A2[PTS_PER_WG * 960];

    const int tid   = threadIdx.x;
    const int wv    = tid >> 6;       // wave id 0..3
    const int lane  = tid & 63;
    const int quad  = lane >> 4;      // 0..3
    const int r16   = lane & 15;
    const int wg    = blockIdx.x;

    const int m32   = lane & 31;      // neighbor index for w-compute
    const int khalf = lane >> 5;      // 0/1

    // hoist this lane's 8 kernel points (identical for all 4 points)
    float kpx[8], kpy[8], kpz[8];
    #pragma unroll
    for (int kk = 0; kk < 8; ++kk) {
        const int k  = kk * 2 + khalf;          // 0..15
        const int kc = (k < 15) ? k : 14;
        kpx[kk] = kp[kc * 3 + 0];
        kpy[kk] = kp[kc * 3 + 1];
        kpz[kk] = kp[kc * 3 + 2];
    }

    // xs write base (elems): lane's float4 = x[m = it*4 + (lane>>4)][c = (lane&15)*4 ..+3]
    // -> subtile slot (it*4 + ((lane>>2)&3)), row (lane>>4), col4 (lane&3)
    const int xwb = ((lane >> 2) & 3) * 64 + (lane >> 4) * 16 + (lane & 3) * 4;
    // tr-read base (bytes): group quad reads subtile slot (8*quad + t) linearly, 8 B/lane
    const unsigned xsbase = (unsigned)(unsigned long long)(&xs[wv][0]);
    const unsigned xa = xsbase + (unsigned)(quad * 1024 + r16 * 8);

    // ================= stage 1: each wave handles 4 points (no barriers) =============
    for (int i = 0; i < 4; ++i) {
        const int  p = wv * 4 + i;
        const long n = (long)wg * PTS_PER_WG + p;

        // issue coalesced x loads early; consumed after geometry (latency overlap)
        const float4* xsrc = (const float4*)(x + n * 2048) + lane;
        float4 xr[8];
        #pragma unroll
        for (int it = 0; it < 8; ++it) xr[it] = xsrc[it * 64];

        // ---- geometry -> w[k][m32] (bf16 into wa[wv]) ----
        const float qx = q_pts[n * 3 + 0];
        const float qy = q_pts[n * 3 + 1];
        const float qz = q_pts[n * 3 + 2];
        const float rx = neighbors[n * 96 + m32 * 3 + 0] - qx;
        const float ry = neighbors[n * 96 + m32 * 3 + 1] - qy;
        const float rz = neighbors[n * 96 + m32 * 3 + 2] - qz;
        #pragma unroll
        for (int kk = 0; kk < 8; ++kk) {
            const int k = kk * 2 + khalf;        // 0..15 (k=15 is zero padding)
            const float dx = rx - kpx[kk];
            const float dy = ry - kpy[kk];
            const float dz = rz - kpz[kk];
            float w = 1.0f - sqrtf(dx * dx + dy * dy + dz * dz) * KP_INV;
            w = (k < 15) ? fmaxf(w, 0.0f) : 0.0f;
            wa[wv][k * 40 + m32] = (unsigned short)fbf(w);
        }
        // wave-local cross-lane RAW through LDS: DS pipe is in-order; compiler adds lgkmcnt.

        // ---- B frag: w[k = r16][m = quad*8 + j] ----
        const bf16x8 wf = *(const bf16x8*)&wa[wv][r16 * 40 + quad * 8];

        // ---- convert + stage x into subtiled LDS (8 x ds_write_b64) ----
        #pragma unroll
        for (int it = 0; it < 8; ++it) {
            short4v sv = { fbf(xr[it].x), fbf(xr[it].y), fbf(xr[it].z), fbf(xr[it].w) };
            *(short4v*)&xs[wv][it * 256 + xwb] = sv;
        }

        // ---- HW-transpose reads: xfrag[j] = x[m = quad*8 + j][c = t*16 + r16] ----
        // tile t at byte offset t*128, m+4 half at +512.
        short4v t0, t1, t2, t3, t4, t5, t6, t7;
        asm volatile("ds_read_b64_tr_b16 %0, %1"            : "=v"(t0) : "v"(xa) : "memory");
        asm volatile("ds_read_b64_tr_b16 %0, %1 offset:512" : "=v"(t1) : "v"(xa) : "memory");
        asm volatile("ds_read_b64_tr_b16 %0, %1 offset:128" : "=v"(t2) : "v"(xa) : "memory");
        asm volatile("ds_read_b64_tr_b16 %0, %1 offset:640" : "=v"(t3) : "v"(xa) : "memory");
        asm volatile("ds_read_b64_tr_b16 %0, %1 offset:256" : "=v"(t4) : "v"(xa) : "memory");
        asm volatile("ds_read_b64_tr_b16 %0, %1 offset:768" : "=v"(t5) : "v"(xa) : "memory");
        asm volatile("ds_read_b64_tr_b16 %0, %1 offset:384" : "=v"(t6) : "v"(xa) : "memory");
        asm volatile("ds_read_b64_tr_b16 %0, %1 offset:896" : "=v"(t7) : "v"(xa) : "memory");
        asm volatile("s_waitcnt lgkmcnt(0)" ::: "memory");
        __builtin_amdgcn_sched_barrier(0);   // keep MFMAs below the wait (rule #18)

        // ---- 4 Cin tiles: D = x^T @ w^T -> weighted^T, spill to A2 as b64 ----
        #pragma unroll
        for (int t = 0; t < 4; ++t) {
            const short4v lo = (t == 0) ? t0 : (t == 1) ? t2 : (t == 2) ? t4 : t6;
            const short4v hi = (t == 0) ? t1 : (t == 1) ? t3 : (t == 2) ? t5 : t7;
            const bf16x8 xf = __builtin_shufflevector(lo, hi, 0, 1, 2, 3, 4, 5, 6, 7);
            f32x4 acc = {0.f, 0.f, 0.f, 0.f};
            acc = __builtin_amdgcn_mfma_f32_16x16x32_bf16(xf, wf, acc, 0, 0, 0);
            // D layout: col k = r16, row c = t*16 + quad*4 + reg (reg-contiguous in k2!)
            if (r16 < 15) {                      // k=15 is zero padding, not stored
                const int ch  = r16 * 8 + t * 2 + (quad >> 1);   // k2 >> 3
                const int sig = ch ^ ((p ^ r16) & 7);            // bank-spread swizzle
                short4v ov = { fbf(acc[0]), fbf(acc[1]), fbf(acc[2]), fbf(acc[3]) };
                *(short4v*)&A2[p * 960 + sig * 8 + (quad & 1) * 4] = ov;
            }
        }
    }

    __syncthreads();  // all 16 points' weighted visible to all waves

    // ================= stage 2: out[16 pts][64] = weighted @ Wflat ==========
    const int d = wv * 16 + r16;
    f32x4 oacc = {0.f, 0.f, 0.f, 0.f};
    if (wp) {
        #pragma unroll 2
        for (int kk = 0; kk < 30; ++kk) {
            const int ch  = kk * 4 + quad;                       // 0..119
            const int sig = ch ^ ((r16 ^ (ch >> 3)) & 7);        // matches stage-1 sigma
            const bf16x8 a2 = *(const bf16x8*)&A2[r16 * 960 + sig * 8];
            const bf16x8 bw = *(const bf16x8*)(wp + (ch * 64 + d) * 8);  // dwordx4
            oacc = __builtin_amdgcn_mfma_f32_16x16x32_bf16(a2, bw, oacc, 0, 0, 0);
        }
    } else {
        // fallback: workspace unavailable -> convert weights in-kernel (old path)
        for (int kk = 0; kk < 30; ++kk) {
            const int ch  = kk * 4 + quad;
            const int sig = ch ^ ((r16 ^ (ch >> 3)) & 7);
            const bf16x8 a2 = *(const bf16x8*)&A2[r16 * 960 + sig * 8];
            const float* wsrc = weights + (kk * 32 + quad * 8) * 64 + d;
            bf16x8 bw;
            #pragma unroll
            for (int j = 0; j < 8; ++j) bw[j] = fbf(wsrc[j * 64]);
            oacc = __builtin_amdgcn_mfma_f32_16x16x32_bf16(a2, bw, oacc, 0, 0, 0);
        }
    }

    // D layout: col d = lane&15 (+wave tile), row p = quad*4+reg
    #pragma unroll
    for (int reg = 0; reg < 4; ++reg) {
        const int pp = quad * 4 + reg;
        out[((long)wg * PTS_PER_WG + pp) * 64 + d] = oacc[reg];
    }
}

extern "C" void kernel_launch(void* const* d_in, const int* in_sizes, int n_in,
                              void* d_out, int out_size, void* d_ws, size_t ws_size,
                              hipStream_t stream) {
    // setup_inputs order: q_pts, s_pts, neighbors, neighb_inds, x, kernel_points, weights
    const float* q_pts     = (const float*)d_in[0];
    // d_in[1] s_pts      : unused by reference
    const float* neighbors = (const float*)d_in[2];
    // d_in[3] neighb_inds: unused by reference
    const float* x         = (const float*)d_in[4];
    const float* kp        = (const float*)d_in[5];
    const float* weights   = (const float*)d_in[6];
    float* out = (float*)d_out;

    unsigned short* wp = (d_ws && ws_size >= (size_t)(WP_ELEMS * 2))
                       ? (unsigned short*)d_ws : nullptr;
    if (wp) prep_weights<<<dim3(120), dim3(512), 0, stream>>>(weights, wp);

    dim3 grid(NPTS / PTS_PER_WG);   // 50000/16 = 3125, exact
    kpconv_kernel<<<grid, 256, 0, stream>>>(q_pts, neighbors, x, kp, weights, wp, out);
}